// Round 1
// baseline (2778.019 us; speedup 1.0000x reference)
//
#include <hip/hip_runtime.h>
#include <hip/hip_bf16.h>

using bf16 = __hip_bfloat16;

#define BM 64
#define BN 64
#define BK 16
#define LDSS 72   // 64 + 8 pad; row stride 288B stays 16B-aligned for float4 LDS reads

__device__ __forceinline__ float to_f(const float* p) { return *p; }
__device__ __forceinline__ float to_f(const bf16* p)  { return __bfloat162float(*p); }

__device__ __forceinline__ void st_c(float* p, float v) { *p = v; }
__device__ __forceinline__ void st_c(bf16* p, float v)  { *p = __float2bfloat16(v); }

// C[m][n] = scale * sum_k A[m][k] * B[k][n] (+ bias[n])
// A is MxK row-major (k-contig).
// B_KCONTIG=true : B is NxK row-major (k-contig)  -> "NT" gemm (x @ W^T, Q @ K^T)
// B_KCONTIG=false: B is KxN row-major (n-contig)  -> "NN" gemm (P @ V)
template <typename TA, typename TB, typename TC, bool B_KCONTIG, bool HAS_BIAS>
__global__ __launch_bounds__(256, 2)
void gemm_kernel(const TA* __restrict__ A, const TB* __restrict__ Bm,
                 const float* __restrict__ bias, TC* __restrict__ C,
                 int M, int N, int K,
                 long sA, long sB, long sC, float scale)
{
    __shared__ float As[BK][LDSS];  // [k][m]
    __shared__ float Bs[BK][LDSS];  // [k][n]

    const int bz = blockIdx.z;
    A  += (long)bz * sA;
    Bm += (long)bz * sB;
    C  += (long)bz * sC;

    const int tid = threadIdx.x;   // 0..255
    const int tx  = tid & 15;
    const int ty  = tid >> 4;
    const int m0  = blockIdx.x * BM;
    const int n0  = blockIdx.y * BN;

    float acc[4][4];
#pragma unroll
    for (int i = 0; i < 4; ++i)
#pragma unroll
        for (int j = 0; j < 4; ++j) acc[i][j] = 0.0f;

    for (int k0 = 0; k0 < K; k0 += BK) {
        // ---- stage A tile: 64(m) x 16(k), transpose into As[k][m]
        {
            const int r  = tid >> 2;        // 0..63 (m within tile)
            const int kk = (tid & 3) << 2;  // 0,4,8,12
            const TA* src = A + (long)(m0 + r) * K + (k0 + kk);
#pragma unroll
            for (int i = 0; i < 4; ++i) As[kk + i][r] = to_f(src + i);
        }
        // ---- stage B tile
        if (B_KCONTIG) {
            const int r  = tid >> 2;        // 0..63 (n within tile)
            const int kk = (tid & 3) << 2;
            const TB* src = Bm + (long)(n0 + r) * K + (k0 + kk);
#pragma unroll
            for (int i = 0; i < 4; ++i) Bs[kk + i][r] = to_f(src + i);
        } else {
            const int kk = tid >> 4;        // 0..15 (k within tile)
            const int nn = (tid & 15) << 2; // 0..60
            const TB* src = Bm + (long)(k0 + kk) * N + (n0 + nn);
#pragma unroll
            for (int i = 0; i < 4; ++i) Bs[kk][nn + i] = to_f(src + i);
        }
        __syncthreads();

#pragma unroll
        for (int kk = 0; kk < BK; ++kk) {
            const float4 av = *reinterpret_cast<const float4*>(&As[kk][ty << 2]);
            const float4 bv = *reinterpret_cast<const float4*>(&Bs[kk][tx << 2]);
            const float a[4] = {av.x, av.y, av.z, av.w};
            const float b[4] = {bv.x, bv.y, bv.z, bv.w};
#pragma unroll
            for (int i = 0; i < 4; ++i)
#pragma unroll
                for (int j = 0; j < 4; ++j)
                    acc[i][j] = fmaf(a[i], b[j], acc[i][j]);
        }
        __syncthreads();
    }

    // ---- epilogue
#pragma unroll
    for (int i = 0; i < 4; ++i) {
        const int row = m0 + (ty << 2) + i;
        TC* crow = C + (long)row * N + (n0 + (tx << 2));
#pragma unroll
        for (int j = 0; j < 4; ++j) {
            float v = acc[i][j] * scale;
            if (HAS_BIAS) v += bias[n0 + (tx << 2) + j];
            st_c(crow + j, v);
        }
    }
}

// In-place masked softmax over rows of S (B*Srows rows, each Slen bf16).
// mask[b][j] != 0  => key j masked out for batch b.
__global__ __launch_bounds__(256)
void softmax_kernel(bf16* __restrict__ Smat, const int* __restrict__ mask, int Slen)
{
    const int row = blockIdx.x;          // b * Slen_rows + q
    const int b   = row / Slen;          // rows per batch == Slen (S x S scores)
    bf16* srow = Smat + (long)row * Slen;
    const int* mrow = mask + (long)b * Slen;

    const int tid  = threadIdx.x;
    const int lane = tid & 63;
    const int wid  = tid >> 6;

    float vals[8];
    float mx = -INFINITY;
#pragma unroll
    for (int i = 0; i < 8; ++i) {
        const int j = tid + (i << 8);
        float v = __bfloat162float(srow[j]);
        if (mrow[j] != 0) v = -INFINITY;
        vals[i] = v;
        mx = fmaxf(mx, v);
    }

    __shared__ float red[4];
    // block max
#pragma unroll
    for (int o = 32; o > 0; o >>= 1) mx = fmaxf(mx, __shfl_xor(mx, o, 64));
    if (lane == 0) red[wid] = mx;
    __syncthreads();
    mx = fmaxf(fmaxf(red[0], red[1]), fmaxf(red[2], red[3]));
    __syncthreads();

    float sum = 0.0f;
#pragma unroll
    for (int i = 0; i < 8; ++i) {
        const float e = __expf(vals[i] - mx);   // exp(-inf - mx) = 0 for masked
        vals[i] = e;
        sum += e;
    }
#pragma unroll
    for (int o = 32; o > 0; o >>= 1) sum += __shfl_xor(sum, o, 64);
    if (lane == 0) red[wid] = sum;
    __syncthreads();
    sum = red[0] + red[1] + red[2] + red[3];

    const float inv = 1.0f / sum;
#pragma unroll
    for (int i = 0; i < 8; ++i) {
        const int j = tid + (i << 8);
        srow[j] = __float2bfloat16(vals[i] * inv);
    }
}

extern "C" void kernel_launch(void* const* d_in, const int* in_sizes, int n_in,
                              void* d_out, int out_size, void* d_ws, size_t ws_size,
                              hipStream_t stream)
{
    const float* hidden = (const float*)d_in[0];
    const int*   mask   = (const int*)d_in[1];   // bool -> int32 per harness convention
    const float* Wq_w   = (const float*)d_in[2];
    const float* Wq_b   = (const float*)d_in[3];
    const float* Wk_w   = (const float*)d_in[4];
    const float* Wk_b   = (const float*)d_in[5];
    float* out = (float*)d_out;

    const int B = 8, S = 2048, H = 1024;
    const int M = B * S;   // 16384

    // ws layout: Q bf16 (M*H) | K bf16 (M*H) | Scores bf16 (B*S*S) = 33.5+33.5+67 MB
    bf16* Qb = (bf16*)d_ws;
    bf16* Kb = Qb + (size_t)M * H;
    bf16* Sb = Kb + (size_t)M * H;

    const dim3 blk(256);

    // Q = X @ Wq^T + bq   (bf16 out)
    gemm_kernel<float, float, bf16, true, true>
        <<<dim3(M / BM, H / BN, 1), blk, 0, stream>>>(
            hidden, Wq_w, Wq_b, Qb, M, H, H, 0, 0, 0, 1.0f);

    // K = X @ Wk^T + bk   (bf16 out)
    gemm_kernel<float, float, bf16, true, true>
        <<<dim3(M / BM, H / BN, 1), blk, 0, stream>>>(
            hidden, Wk_w, Wk_b, Kb, M, H, H, 0, 0, 0, 1.0f);

    // Scores_b = (Q_b @ K_b^T) / sqrt(H)   (bf16, per batch)
    gemm_kernel<bf16, bf16, bf16, true, false>
        <<<dim3(S / BM, S / BN, B), blk, 0, stream>>>(
            Qb, Kb, nullptr, Sb, S, S, H,
            (long)S * H, (long)S * H, (long)S * S, 1.0f / 32.0f);

    // masked softmax over key dim, in place
    softmax_kernel<<<dim3(B * S), blk, 0, stream>>>(Sb, mask, S);

    // Out_b = P_b @ X_b   (fp32 out)
    gemm_kernel<bf16, float, float, false, false>
        <<<dim3(S / BM, H / BN, B), blk, 0, stream>>>(
            Sb, hidden, nullptr, out, S, H, S,
            (long)S * S, (long)S * H, (long)S * H, 1.0f);
}

// Round 2
// 478.063 us; speedup vs baseline: 5.8110x; 5.8110x over previous
//
#include <hip/hip_runtime.h>
#include <hip/hip_bf16.h>

using bf16 = __hip_bfloat16;

using frag_ab = __attribute__((ext_vector_type(8))) short;  // 8 bf16 = 4 VGPRs
using frag_cd = __attribute__((ext_vector_type(4))) float;  // 4 fp32 acc

#define TM 128
#define TN 128
#define TK 32

__device__ __forceinline__ unsigned short f2bu(float f) {
    bf16 h = __float2bfloat16(f);
    return *(unsigned short*)&h;
}

__device__ __forceinline__ void st_c(float* p, float v) { *p = v; }
__device__ __forceinline__ void st_c(bf16* p, float v)  { *p = __float2bfloat16(v); }

// 16B-per-lane async global->LDS. LDS dest must be wave-uniform-base + lane*16,
// which holds because thread t's lds addr is As_flat + t*16B (contiguous).
__device__ __forceinline__ void load16(const bf16* g, bf16* l) {
    __builtin_amdgcn_global_load_lds(
        (const __attribute__((address_space(1))) unsigned int*)g,
        (__attribute__((address_space(3))) unsigned int*)l,
        16, 0, 0);
}

// C[m][n] = scale * sum_k A[m][k]*B[n][k] (+ bias[n]).  A: MxK k-contig, B: NxK k-contig.
// m97-style: 128x128 tile, BK=32, 4 waves in 2x2, each wave 64x64 via 4x4 MFMA 16x16x32.
template <typename TC, bool HAS_BIAS>
__global__ __launch_bounds__(256)
void mfma_gemm_nt(const bf16* __restrict__ A, const bf16* __restrict__ B,
                  const float* __restrict__ bias, TC* __restrict__ C,
                  int M, int N, int K, long sA, long sB, long sC, float scale)
{
    __shared__ bf16 As[TM][TK];   // 8 KB, no pad (global_load_lds layout constraint)
    __shared__ bf16 Bs[TN][TK];   // 8 KB

    const int bz = blockIdx.z;
    const bf16* Ab = A + (long)bz * sA;
    const bf16* Bb = B + (long)bz * sB;
    TC* Cb = C + (long)bz * sC;

    const int t  = threadIdx.x;
    const int m0 = blockIdx.x * TM;
    const int n0 = blockIdx.y * TN;

    // staging: thread t covers 16B at LDS byte offset t*16 (rows of 64B => 4 threads/row)
    const int srow  = t >> 2;          // 0..63
    const int skoff = (t & 3) << 3;    // 0,8,16,24 (bf16 elems)
    const bf16* ga0 = Ab + (long)(m0 + srow) * K + skoff;
    const bf16* ga1 = ga0 + (long)64 * K;
    const bf16* gb0 = Bb + (long)(n0 + srow) * K + skoff;
    const bf16* gb1 = gb0 + (long)64 * K;
    bf16* la0 = &As[srow][skoff];
    bf16* la1 = &As[srow + 64][skoff];
    bf16* lb0 = &Bs[srow][skoff];
    bf16* lb1 = &Bs[srow + 64][skoff];

    const int wave = t >> 6;
    const int lane = t & 63;
    const int wm   = (wave & 1) * 64;
    const int wn   = (wave >> 1) * 64;
    const int lrow = lane & 15;        // n (or m) within a 16-tile
    const int quad = lane >> 4;        // k-group for A/B frags; row-group for C

    frag_cd acc[4][4] = {};

    for (int k0 = 0; k0 < K; k0 += TK) {
        load16(ga0, la0); load16(ga1, la1);
        load16(gb0, lb0); load16(gb1, lb1);
        ga0 += TK; ga1 += TK; gb0 += TK; gb1 += TK;
        __syncthreads();   // drains vmcnt -> LDS tiles valid

        frag_ab af[4], bfv[4];
#pragma unroll
        for (int i = 0; i < 4; ++i)
            af[i] = *(const frag_ab*)&As[wm + i * 16 + lrow][quad * 8];
#pragma unroll
        for (int j = 0; j < 4; ++j)
            bfv[j] = *(const frag_ab*)&Bs[wn + j * 16 + lrow][quad * 8];
#pragma unroll
        for (int i = 0; i < 4; ++i)
#pragma unroll
            for (int j = 0; j < 4; ++j)
                acc[i][j] = __builtin_amdgcn_mfma_f32_16x16x32_bf16(
                    af[i], bfv[j], acc[i][j], 0, 0, 0);
        __syncthreads();   // protect LDS before next stage
    }

    // epilogue: C/D layout col=lane&15, row=quad*4+reg  [m89-verified]
#pragma unroll
    for (int j = 0; j < 4; ++j) {
        const int col = n0 + wn + j * 16 + lrow;
        const float bv = HAS_BIAS ? bias[col] : 0.0f;
#pragma unroll
        for (int i = 0; i < 4; ++i) {
            const int rbase = m0 + wm + i * 16 + quad * 4;
#pragma unroll
            for (int r = 0; r < 4; ++r) {
                const float v = acc[i][j][r] * scale + bv;
                st_c(&Cb[(long)(rbase + r) * N + col], v);
            }
        }
    }
}

// fp32 X[b][s][h] -> bf16 Xb[b][s][h] and bf16 XT[b][h][s], 64x64 tiles.
__global__ __launch_bounds__(256)
void convert_transpose(const float* __restrict__ X, bf16* __restrict__ Xb,
                       bf16* __restrict__ XT, int S, int H)
{
    __shared__ unsigned short tile[64][72];
    const int b = blockIdx.z;
    const float* Xp = X + (long)b * S * H;
    bf16* Xbp = Xb + (long)b * S * H;
    bf16* XTp = XT + (long)b * H * S;
    const int h0 = blockIdx.x * 64, s0 = blockIdx.y * 64;
    const int t = threadIdx.x;
    const int r  = t >> 4;          // 0..15
    const int c4 = (t & 15) * 4;    // 0..60

#pragma unroll
    for (int p = 0; p < 4; ++p) {
        const int row = r + p * 16;
        const float4 v = *(const float4*)&Xp[(long)(s0 + row) * H + h0 + c4];
        ushort4 u;
        u.x = f2bu(v.x); u.y = f2bu(v.y); u.z = f2bu(v.z); u.w = f2bu(v.w);
        *(ushort4*)&tile[row][c4] = u;
        *(ushort4*)&Xbp[(long)(s0 + row) * H + h0 + c4] = u;
    }
    __syncthreads();
#pragma unroll
    for (int p = 0; p < 4; ++p) {
        const int hrow = r + p * 16;
        ushort4 u;
        u.x = tile[c4 + 0][hrow];
        u.y = tile[c4 + 1][hrow];
        u.z = tile[c4 + 2][hrow];
        u.w = tile[c4 + 3][hrow];
        *(ushort4*)&XTp[(long)(h0 + hrow) * S + s0 + c4] = u;
    }
}

__global__ __launch_bounds__(256)
void convert_bf16(const float* __restrict__ in, bf16* __restrict__ out, int n4)
{
    const int i = blockIdx.x * 256 + threadIdx.x;
    if (i < n4) {
        const float4 v = ((const float4*)in)[i];
        ushort4 u;
        u.x = f2bu(v.x); u.y = f2bu(v.y); u.z = f2bu(v.z); u.w = f2bu(v.w);
        ((ushort4*)out)[i] = u;
    }
}

// In-place masked softmax over rows (each row Slen=2048 bf16), 16B vector loads.
__global__ __launch_bounds__(256)
void softmax_kernel(bf16* __restrict__ Smat, const int* __restrict__ mask, int Slen)
{
    const int row = blockIdx.x;
    const int b   = row / Slen;
    bf16* srow = Smat + (long)row * Slen;
    const int* mrow = mask + (long)b * Slen;

    const int t    = threadIdx.x;
    const int lane = t & 63;
    const int wid  = t >> 6;

    // 8 contiguous bf16 per thread
    ushort4 u0 = ((const ushort4*)srow)[t * 2];
    ushort4 u1 = ((const ushort4*)srow)[t * 2 + 1];
    int4 q0 = ((const int4*)mrow)[t * 2];
    int4 q1 = ((const int4*)mrow)[t * 2 + 1];

    float vals[8];
    {
        const unsigned short us[8] = {u0.x, u0.y, u0.z, u0.w, u1.x, u1.y, u1.z, u1.w};
        const int ms[8] = {q0.x, q0.y, q0.z, q0.w, q1.x, q1.y, q1.z, q1.w};
#pragma unroll
        for (int i = 0; i < 8; ++i) {
            unsigned int w = (unsigned int)us[i] << 16;
            float v = *(float*)&w;
            vals[i] = ms[i] ? -INFINITY : v;
        }
    }

    float mx = vals[0];
#pragma unroll
    for (int i = 1; i < 8; ++i) mx = fmaxf(mx, vals[i]);

    __shared__ float red[4];
#pragma unroll
    for (int o = 32; o > 0; o >>= 1) mx = fmaxf(mx, __shfl_xor(mx, o, 64));
    if (lane == 0) red[wid] = mx;
    __syncthreads();
    mx = fmaxf(fmaxf(red[0], red[1]), fmaxf(red[2], red[3]));
    __syncthreads();

    float sum = 0.0f;
#pragma unroll
    for (int i = 0; i < 8; ++i) {
        const float e = __expf(vals[i] - mx);
        vals[i] = e;
        sum += e;
    }
#pragma unroll
    for (int o = 32; o > 0; o >>= 1) sum += __shfl_xor(sum, o, 64);
    if (lane == 0) red[wid] = sum;
    __syncthreads();
    sum = red[0] + red[1] + red[2] + red[3];

    const float inv = 1.0f / sum;
    ushort4 o0, o1;
    o0.x = f2bu(vals[0] * inv); o0.y = f2bu(vals[1] * inv);
    o0.z = f2bu(vals[2] * inv); o0.w = f2bu(vals[3] * inv);
    o1.x = f2bu(vals[4] * inv); o1.y = f2bu(vals[5] * inv);
    o1.z = f2bu(vals[6] * inv); o1.w = f2bu(vals[7] * inv);
    ((ushort4*)srow)[t * 2]     = o0;
    ((ushort4*)srow)[t * 2 + 1] = o1;
}

extern "C" void kernel_launch(void* const* d_in, const int* in_sizes, int n_in,
                              void* d_out, int out_size, void* d_ws, size_t ws_size,
                              hipStream_t stream)
{
    const float* hidden = (const float*)d_in[0];
    const int*   mask   = (const int*)d_in[1];
    const float* Wq_w   = (const float*)d_in[2];
    const float* Wq_b   = (const float*)d_in[3];
    const float* Wk_w   = (const float*)d_in[4];
    const float* Wk_b   = (const float*)d_in[5];
    float* out = (float*)d_out;

    const int B = 8, S = 2048, H = 1024;
    const int M = B * S;               // 16384
    const long MH = (long)M * H;       // 16.7M elems

    // ws layout (bf16 elems): Qb | Kb | XbT | Sb ; Xb+Wqb+Wkb aliased inside Sb
    // (Xb/W dead before scores gemm writes Sb). Total = 3*33.5MB + 67MB = 168MB.
    bf16* Qb  = (bf16*)d_ws;
    bf16* Kb  = Qb + MH;
    bf16* XbT = Kb + MH;
    bf16* Sb  = XbT + MH;
    bf16* Xb  = Sb;                    // aliased
    bf16* Wqb = Xb + MH;
    bf16* Wkb = Wqb + (long)H * H;

    const dim3 blk(256);

    // X -> bf16 (+ transpose for PV's B operand)
    convert_transpose<<<dim3(H / 64, S / 64, B), blk, 0, stream>>>(hidden, Xb, XbT, S, H);
    convert_bf16<<<dim3((H * H / 4 + 255) / 256), blk, 0, stream>>>(Wq_w, Wqb, H * H / 4);
    convert_bf16<<<dim3((H * H / 4 + 255) / 256), blk, 0, stream>>>(Wk_w, Wkb, H * H / 4);

    // Q = Xb @ Wqb^T + bq ; K = Xb @ Wkb^T + bk
    mfma_gemm_nt<bf16, true><<<dim3(M / TM, H / TN, 1), blk, 0, stream>>>(
        Xb, Wqb, Wq_b, Qb, M, H, H, 0, 0, 0, 1.0f);
    mfma_gemm_nt<bf16, true><<<dim3(M / TM, H / TN, 1), blk, 0, stream>>>(
        Xb, Wkb, Wk_b, Kb, M, H, H, 0, 0, 0, 1.0f);

    // Scores_b = (Q_b @ K_b^T) / 32
    mfma_gemm_nt<bf16, false><<<dim3(S / TM, S / TN, B), blk, 0, stream>>>(
        Qb, Kb, nullptr, Sb, S, S, H,
        (long)S * H, (long)S * H, (long)S * S, 1.0f / 32.0f);

    // masked softmax in place
    softmax_kernel<<<dim3(B * S), blk, 0, stream>>>(Sb, mask, S);

    // Out_b = P_b @ X_b  (B operand = XbT, k-contig)
    mfma_gemm_nt<float, false><<<dim3(S / TM, H / TN, B), blk, 0, stream>>>(
        Sb, XbT, nullptr, out, S, H, S,
        (long)S * S, (long)H * S, (long)S * H, 1.0f);
}

// Round 3
// 455.675 us; speedup vs baseline: 6.0965x; 1.0491x over previous
//
#include <hip/hip_runtime.h>
#include <hip/hip_bf16.h>

using bf16 = __hip_bfloat16;

using frag_ab = __attribute__((ext_vector_type(8))) short;  // 8 bf16 = 4 VGPRs
using frag_cd = __attribute__((ext_vector_type(4))) float;  // 4 fp32 acc

#define TM 128
#define TN 128
#define TK 32

__device__ __forceinline__ unsigned short f2bu(float f) {
    bf16 h = __float2bfloat16(f);
    return *(unsigned short*)&h;
}

__device__ __forceinline__ void st_c(float* p, float v) { *p = v; }
__device__ __forceinline__ void st_c(bf16* p, float v)  { *p = __float2bfloat16(v); }

// 16B-per-lane async global->LDS. Per-wave LDS dest = uniform base + lane*16 (required).
__device__ __forceinline__ void load16(const bf16* g, bf16* l) {
    __builtin_amdgcn_global_load_lds(
        (const __attribute__((address_space(1))) unsigned int*)g,
        (__attribute__((address_space(3))) unsigned int*)l,
        16, 0, 0);
}

// C[m][n] = scale * sum_k A[m][k]*B[n][k] (+ bias[n]) (+ -inf where mask[n]!=0).
// A: M x K rows k-contig with row stride lda; B: N x K rows k-contig stride ldb.
// 128x128 tile, BK=32, 4 waves 2x2, each wave 64x64 via 4x4 MFMA 16x16x32.
// Double-buffered LDS: stage k+1 issued BEFORE compute of k; single barrier/iter.
template <typename TC, bool HAS_BIAS, bool MASK>
__global__ __launch_bounds__(256)
void mfma_gemm_nt(const bf16* __restrict__ A, const bf16* __restrict__ B,
                  const float* __restrict__ bias, const int* __restrict__ mask,
                  TC* __restrict__ C, int N, int K, int lda, int ldb, int ldc,
                  long sA, long sB, long sC, long sM, float scale)
{
    __shared__ bf16 As[2][TM][TK];   // 2 x 8 KB
    __shared__ bf16 Bs[2][TN][TK];   // 2 x 8 KB

    const int bz = blockIdx.z;
    const bf16* Ab = A + (long)bz * sA;
    const bf16* Bb = B + (long)bz * sB;
    TC* Cb = C + (long)bz * sC;
    const int* maskb = MASK ? (mask + (long)bz * sM) : nullptr;

    const int t  = threadIdx.x;
    const int m0 = blockIdx.x * TM;
    const int n0 = blockIdx.y * TN;

    // staging: thread t covers 16B at LDS byte offset base + t*16
    const int srow  = t >> 2;          // 0..63
    const int skoff = (t & 3) << 3;    // 0,8,16,24 bf16 elems
    const bf16* ga0 = Ab + (long)(m0 + srow) * lda + skoff;
    const bf16* ga1 = ga0 + (long)64 * lda;
    const bf16* gb0 = Bb + (long)(n0 + srow) * ldb + skoff;
    const bf16* gb1 = gb0 + (long)64 * ldb;

    const int wave = t >> 6;
    const int lane = t & 63;
    const int wm   = (wave & 1) * 64;
    const int wn   = (wave >> 1) * 64;
    const int lrow = lane & 15;
    const int quad = lane >> 4;

    frag_cd acc[4][4] = {};

#define STAGE(buf)                                         \
    do {                                                   \
        load16(ga0, &As[buf][srow][skoff]);                \
        load16(ga1, &As[buf][srow + 64][skoff]);           \
        load16(gb0, &Bs[buf][srow][skoff]);                \
        load16(gb1, &Bs[buf][srow + 64][skoff]);           \
        ga0 += TK; ga1 += TK; gb0 += TK; gb1 += TK;        \
    } while (0)

    STAGE(0);
    __syncthreads();           // buf0 ready

    int cur = 0;
    for (int k0 = 0; k0 < K; k0 += TK) {
        if (k0 + TK < K) STAGE(cur ^ 1);   // async prefetch, in flight during compute

        frag_ab af[4], bfv[4];
#pragma unroll
        for (int i = 0; i < 4; ++i)
            af[i] = *(const frag_ab*)&As[cur][wm + i * 16 + lrow][quad * 8];
#pragma unroll
        for (int j = 0; j < 4; ++j)
            bfv[j] = *(const frag_ab*)&Bs[cur][wn + j * 16 + lrow][quad * 8];
#pragma unroll
        for (int i = 0; i < 4; ++i)
#pragma unroll
            for (int j = 0; j < 4; ++j)
                acc[i][j] = __builtin_amdgcn_mfma_f32_16x16x32_bf16(
                    af[i], bfv[j], acc[i][j], 0, 0, 0);

        __syncthreads();   // drains prefetch (buf cur^1 ready) + protects buf cur
        cur ^= 1;
    }
#undef STAGE

    // epilogue: C/D layout col=lane&15, row=quad*4+reg  [m89-verified]
#pragma unroll
    for (int j = 0; j < 4; ++j) {
        const int col = n0 + wn + j * 16 + lrow;
        const float bv = HAS_BIAS ? bias[col] : 0.0f;
        const bool msk = MASK ? (maskb[col] != 0) : false;
#pragma unroll
        for (int i = 0; i < 4; ++i) {
            const int rbase = m0 + wm + i * 16 + quad * 4;
#pragma unroll
            for (int r = 0; r < 4; ++r) {
                float v = acc[i][j][r] * scale + bv;
                if (MASK && msk) v = -INFINITY;
                st_c(&Cb[(long)(rbase + r) * ldc + col], v);
            }
        }
    }
}

// fp32 X[b][s][h] -> bf16 Xb[b][s][h] and bf16 XT[b][h][s], 64x64 tiles.
__global__ __launch_bounds__(256)
void convert_transpose(const float* __restrict__ X, bf16* __restrict__ Xb,
                       bf16* __restrict__ XT, int S, int H)
{
    __shared__ unsigned short tile[64][72];
    const int b = blockIdx.z;
    const float* Xp = X + (long)b * S * H;
    bf16* Xbp = Xb + (long)b * S * H;
    bf16* XTp = XT + (long)b * H * S;
    const int h0 = blockIdx.x * 64, s0 = blockIdx.y * 64;
    const int t = threadIdx.x;
    const int r  = t >> 4;
    const int c4 = (t & 15) * 4;

#pragma unroll
    for (int p = 0; p < 4; ++p) {
        const int row = r + p * 16;
        const float4 v = *(const float4*)&Xp[(long)(s0 + row) * H + h0 + c4];
        ushort4 u;
        u.x = f2bu(v.x); u.y = f2bu(v.y); u.z = f2bu(v.z); u.w = f2bu(v.w);
        *(ushort4*)&tile[row][c4] = u;
        *(ushort4*)&Xbp[(long)(s0 + row) * H + h0 + c4] = u;
    }
    __syncthreads();
#pragma unroll
    for (int p = 0; p < 4; ++p) {
        const int hrow = r + p * 16;
        ushort4 u;
        u.x = tile[c4 + 0][hrow];
        u.y = tile[c4 + 1][hrow];
        u.z = tile[c4 + 2][hrow];
        u.w = tile[c4 + 3][hrow];
        *(ushort4*)&XTp[(long)(h0 + hrow) * S + s0 + c4] = u;
    }
}

__global__ __launch_bounds__(256)
void convert_bf16(const float* __restrict__ in, bf16* __restrict__ out, int n4)
{
    const int i = blockIdx.x * 256 + threadIdx.x;
    if (i < n4) {
        const float4 v = ((const float4*)in)[i];
        ushort4 u;
        u.x = f2bu(v.x); u.y = f2bu(v.y); u.z = f2bu(v.z); u.w = f2bu(v.w);
        ((ushort4*)out)[i] = u;
    }
}

__global__ __launch_bounds__(256)
void pack_bias(const float* __restrict__ qb, const float* __restrict__ kb,
               float* __restrict__ out, int H)
{
    const int i = blockIdx.x * 256 + threadIdx.x;
    out[i] = (i < H) ? qb[i] : kb[i - H];
}

// In-place masked softmax over rows (Slen=2048 bf16). Mask pre-applied as -inf.
__global__ __launch_bounds__(256)
void softmax_kernel(bf16* __restrict__ Smat, int Slen)
{
    const int row = blockIdx.x;
    bf16* srow = Smat + (long)row * Slen;

    const int t    = threadIdx.x;
    const int lane = t & 63;
    const int wid  = t >> 6;

    ushort4 u0 = ((const ushort4*)srow)[t * 2];
    ushort4 u1 = ((const ushort4*)srow)[t * 2 + 1];

    float vals[8];
    {
        const unsigned short us[8] = {u0.x, u0.y, u0.z, u0.w, u1.x, u1.y, u1.z, u1.w};
#pragma unroll
        for (int i = 0; i < 8; ++i) {
            unsigned int w = (unsigned int)us[i] << 16;
            vals[i] = *(float*)&w;
        }
    }

    float mx = vals[0];
#pragma unroll
    for (int i = 1; i < 8; ++i) mx = fmaxf(mx, vals[i]);

    __shared__ float red[4];
#pragma unroll
    for (int o = 32; o > 0; o >>= 1) mx = fmaxf(mx, __shfl_xor(mx, o, 64));
    if (lane == 0) red[wid] = mx;
    __syncthreads();
    mx = fmaxf(fmaxf(red[0], red[1]), fmaxf(red[2], red[3]));
    __syncthreads();

    float sum = 0.0f;
#pragma unroll
    for (int i = 0; i < 8; ++i) {
        const float e = __expf(vals[i] - mx);   // exp(-inf - mx) = 0
        vals[i] = e;
        sum += e;
    }
#pragma unroll
    for (int o = 32; o > 0; o >>= 1) sum += __shfl_xor(sum, o, 64);
    if (lane == 0) red[wid] = sum;
    __syncthreads();
    sum = red[0] + red[1] + red[2] + red[3];

    const float inv = 1.0f / sum;
    ushort4 o0, o1;
    o0.x = f2bu(vals[0] * inv); o0.y = f2bu(vals[1] * inv);
    o0.z = f2bu(vals[2] * inv); o0.w = f2bu(vals[3] * inv);
    o1.x = f2bu(vals[4] * inv); o1.y = f2bu(vals[5] * inv);
    o1.z = f2bu(vals[6] * inv); o1.w = f2bu(vals[7] * inv);
    ((ushort4*)srow)[t * 2]     = o0;
    ((ushort4*)srow)[t * 2 + 1] = o1;
}

extern "C" void kernel_launch(void* const* d_in, const int* in_sizes, int n_in,
                              void* d_out, int out_size, void* d_ws, size_t ws_size,
                              hipStream_t stream)
{
    const float* hidden = (const float*)d_in[0];
    const int*   mask   = (const int*)d_in[1];
    const float* Wq_w   = (const float*)d_in[2];
    const float* Wq_b   = (const float*)d_in[3];
    const float* Wk_w   = (const float*)d_in[4];
    const float* Wk_b   = (const float*)d_in[5];
    float* out = (float*)d_out;

    const int B = 8, S = 2048, H = 1024;
    const int M = B * S;               // 16384
    const long MH = (long)M * H;       // 16.7M elems

    // ws (bf16 elems): QK[M][2H] (67MB) | XbT (33.5MB) | Sb (67MB)
    // Xb + Wqb|Wkb (stacked = merged proj B operand) + packed bias aliased inside Sb
    // (all dead before scores gemm writes Sb).
    bf16* QK  = (bf16*)d_ws;
    bf16* XbT = QK + MH * 2;
    bf16* Sb  = XbT + MH;
    bf16* Xb  = Sb;                    // aliased
    bf16* Wb  = Xb + MH;               // [2H][H] = Wq stacked on Wk
    float* biasP = (float*)(Wb + 2L * H * H);  // 2048 floats

    const dim3 blk(256);

    // X -> bf16 (+ transpose for PV's B operand); weights -> bf16 (stacked)
    convert_transpose<<<dim3(H / 64, S / 64, B), blk, 0, stream>>>(hidden, Xb, XbT, S, H);
    convert_bf16<<<dim3(H * H / 1024), blk, 0, stream>>>(Wq_w, Wb, H * H / 4);
    convert_bf16<<<dim3(H * H / 1024), blk, 0, stream>>>(Wk_w, Wb + (long)H * H, H * H / 4);
    pack_bias<<<dim3(2 * H / 256), blk, 0, stream>>>(Wq_b, Wk_b, biasP, H);

    // QK = Xb @ [Wq;Wk]^T + [bq;bk]   (one merged gemm, N = 2H)
    mfma_gemm_nt<bf16, true, false><<<dim3(M / TM, 2 * H / TN, 1), blk, 0, stream>>>(
        Xb, Wb, biasP, nullptr, QK, 2 * H, H, H, H, 2 * H, 0, 0, 0, 0, 1.0f);

    // Scores_b = (Q_b @ K_b^T)/32, mask applied as -inf in epilogue
    mfma_gemm_nt<bf16, false, true><<<dim3(S / TM, S / TN, B), blk, 0, stream>>>(
        QK, QK + H, nullptr, mask, Sb, S, H, 2 * H, 2 * H, S,
        (long)S * 2 * H, (long)S * 2 * H, (long)S * S, S, 1.0f / 32.0f);

    // softmax in place (mask already -inf)
    softmax_kernel<<<dim3(B * S), blk, 0, stream>>>(Sb, S);

    // Out_b = P_b @ X_b  (B operand = XbT, k-contig)
    mfma_gemm_nt<float, false, false><<<dim3(S / TM, H / TN, B), blk, 0, stream>>>(
        Sb, XbT, nullptr, nullptr, out, H, S, S, S, H,
        (long)S * S, (long)H * S, (long)S * H, 0, 1.0f);
}

// Round 4
// 415.939 us; speedup vs baseline: 6.6789x; 1.0955x over previous
//
#include <hip/hip_runtime.h>
#include <hip/hip_bf16.h>

using bf16 = __hip_bfloat16;

using frag_ab = __attribute__((ext_vector_type(8))) short;  // 8 bf16 = 4 VGPRs
using frag_cd = __attribute__((ext_vector_type(4))) float;  // 4 fp32 acc

#define TM 128
#define TN 128
#define TK 32

__device__ __forceinline__ unsigned short f2bu(float f) {
    bf16 h = __float2bfloat16(f);
    return *(unsigned short*)&h;
}

__device__ __forceinline__ void st_c(float* p, float v) { *p = v; }
__device__ __forceinline__ void st_c(bf16* p, float v)  { *p = __float2bfloat16(v); }

// 16B-per-lane async global->LDS. Per-wave LDS dest = uniform base + lane*16 (required).
__device__ __forceinline__ void load16(const bf16* g, bf16* l) {
    __builtin_amdgcn_global_load_lds(
        (const __attribute__((address_space(1))) unsigned int*)g,
        (__attribute__((address_space(3))) unsigned int*)l,
        16, 0, 0);
}

// C[m][n] = scale * sum_k A[m][k]*B[n][k] (+ bias[n]) (+ -inf where mask[n]!=0).
// A: M x K rows k-contig stride lda; B: N x K rows k-contig stride ldb.
// 128x128 tile, BK=32, 4 waves 2x2, each wave 64x64 via 4x4 MFMA 16x16x32.
// Double-buffered LDS; bank-conflict swizzle: LDS slot (row, chunk c) holds global
// 16B-chunk (c - (row>>1)) & 3; reader uses chunk (quad + (lrow>>1)) & 3.
// __launch_bounds__(256,4): force total regs <= 128 (64 AGPR acc + <=64 VGPR)
// -> 4 blocks/CU instead of 3 for latency hiding.
template <typename TC, bool HAS_BIAS, bool MASK>
__global__ __launch_bounds__(256, 4)
void mfma_gemm_nt(const bf16* __restrict__ A, const bf16* __restrict__ B,
                  const float* __restrict__ bias, const int* __restrict__ mask,
                  TC* __restrict__ C, int N, int K, int lda, int ldb, int ldc,
                  long sA, long sB, long sC, long sM, float scale)
{
    __shared__ bf16 As[2][TM][TK];   // 2 x 8 KB
    __shared__ bf16 Bs[2][TN][TK];   // 2 x 8 KB

    const int bz = blockIdx.z;
    const bf16* Ab = A + (long)bz * sA;
    const bf16* Bb = B + (long)bz * sB;
    TC* Cb = C + (long)bz * sC;
    const int* maskb = MASK ? (mask + (long)bz * sM) : nullptr;

    const int t  = threadIdx.x;
    const int m0 = blockIdx.x * TM;
    const int n0 = blockIdx.y * TN;

    // staging: thread t fills LDS slot (srow, chunk c); fetches swizzled global chunk
    const int srow = t >> 2;                           // 0..63
    const int c    = t & 3;                            // 16B chunk in LDS row
    const int gco  = (((c - (srow >> 1)) & 3) << 3);   // global k elem offset (swizzled)
    const int lco  = c << 3;                           // LDS elem offset (linear)
    const bf16* ga0 = Ab + (long)(m0 + srow) * lda + gco;
    const bf16* ga1 = ga0 + (long)64 * lda;            // rows+64: same swizzle (64>>1 ≡ 0 mod 4)
    const bf16* gb0 = Bb + (long)(n0 + srow) * ldb + gco;
    const bf16* gb1 = gb0 + (long)64 * ldb;

    const int wave = t >> 6;
    const int lane = t & 63;
    const int wm   = (wave & 1) * 64;
    const int wn   = (wave >> 1) * 64;
    const int lrow = lane & 15;
    const int quad = lane >> 4;
    // reader-side swizzled chunk: rows wm+i*16+lrow -> (quad + (lrow>>1)) & 3, i-invariant
    const int rco  = (((quad + (lrow >> 1)) & 3) << 3);

    frag_cd acc[4][4] = {};

#define STAGE(buf)                                         \
    do {                                                   \
        load16(ga0, &As[buf][srow][lco]);                  \
        load16(ga1, &As[buf][srow + 64][lco]);             \
        load16(gb0, &Bs[buf][srow][lco]);                  \
        load16(gb1, &Bs[buf][srow + 64][lco]);             \
        ga0 += TK; ga1 += TK; gb0 += TK; gb1 += TK;        \
    } while (0)

    STAGE(0);
    __syncthreads();           // buf0 ready

    int cur = 0;
    for (int k0 = 0; k0 < K; k0 += TK) {
        if (k0 + TK < K) STAGE(cur ^ 1);   // async prefetch, in flight during compute

        frag_ab af[4], bfv[4];
#pragma unroll
        for (int i = 0; i < 4; ++i)
            af[i] = *(const frag_ab*)&As[cur][wm + i * 16 + lrow][rco];
#pragma unroll
        for (int j = 0; j < 4; ++j)
            bfv[j] = *(const frag_ab*)&Bs[cur][wn + j * 16 + lrow][rco];
#pragma unroll
        for (int i = 0; i < 4; ++i)
#pragma unroll
            for (int j = 0; j < 4; ++j)
                acc[i][j] = __builtin_amdgcn_mfma_f32_16x16x32_bf16(
                    af[i], bfv[j], acc[i][j], 0, 0, 0);

        __syncthreads();   // drains prefetch (buf cur^1 ready) + protects buf cur
        cur ^= 1;
    }
#undef STAGE

    // epilogue: C/D layout col=lane&15, row=quad*4+reg  [m89-verified]
#pragma unroll
    for (int j = 0; j < 4; ++j) {
        const int col = n0 + wn + j * 16 + lrow;
        const float bv = HAS_BIAS ? bias[col] : 0.0f;
        const bool msk = MASK ? (maskb[col] != 0) : false;
#pragma unroll
        for (int i = 0; i < 4; ++i) {
            const int rbase = m0 + wm + i * 16 + quad * 4;
#pragma unroll
            for (int r = 0; r < 4; ++r) {
                float v = acc[i][j][r] * scale + bv;
                if (MASK && msk) v = -INFINITY;
                st_c(&Cb[(long)(rbase + r) * ldc + col], v);
            }
        }
    }
}

// fp32 X[b][s][h] -> bf16 Xb[b][s][h] and bf16 XT[b][h][s], 64x64 tiles.
__global__ __launch_bounds__(256)
void convert_transpose(const float* __restrict__ X, bf16* __restrict__ Xb,
                       bf16* __restrict__ XT, int S, int H)
{
    __shared__ unsigned short tile[64][72];
    const int b = blockIdx.z;
    const float* Xp = X + (long)b * S * H;
    bf16* Xbp = Xb + (long)b * S * H;
    bf16* XTp = XT + (long)b * H * S;
    const int h0 = blockIdx.x * 64, s0 = blockIdx.y * 64;
    const int t = threadIdx.x;
    const int r  = t >> 4;
    const int c4 = (t & 15) * 4;

#pragma unroll
    for (int p = 0; p < 4; ++p) {
        const int row = r + p * 16;
        const float4 v = *(const float4*)&Xp[(long)(s0 + row) * H + h0 + c4];
        ushort4 u;
        u.x = f2bu(v.x); u.y = f2bu(v.y); u.z = f2bu(v.z); u.w = f2bu(v.w);
        *(ushort4*)&tile[row][c4] = u;
        *(ushort4*)&Xbp[(long)(s0 + row) * H + h0 + c4] = u;
    }
    __syncthreads();
#pragma unroll
    for (int p = 0; p < 4; ++p) {
        const int hrow = r + p * 16;
        ushort4 u;
        u.x = tile[c4 + 0][hrow];
        u.y = tile[c4 + 1][hrow];
        u.z = tile[c4 + 2][hrow];
        u.w = tile[c4 + 3][hrow];
        *(ushort4*)&XTp[(long)(h0 + hrow) * S + s0 + c4] = u;
    }
}

// both weight matrices -> bf16, contiguous out [2*H*H]
__global__ __launch_bounds__(256)
void convert_w2(const float* __restrict__ wa, const float* __restrict__ wb,
                bf16* __restrict__ out, int n4each)
{
    const int i = blockIdx.x * 256 + threadIdx.x;
    const bool second = i >= n4each;
    const float* src = second ? wb : wa;
    const int j = second ? i - n4each : i;
    const float4 v = ((const float4*)src)[j];
    ushort4 u;
    u.x = f2bu(v.x); u.y = f2bu(v.y); u.z = f2bu(v.z); u.w = f2bu(v.w);
    ((ushort4*)out)[i] = u;
}

__global__ __launch_bounds__(256)
void pack_bias(const float* __restrict__ qb, const float* __restrict__ kb,
               float* __restrict__ out, int H)
{
    const int i = blockIdx.x * 256 + threadIdx.x;
    out[i] = (i < H) ? qb[i] : kb[i - H];
}

// In-place masked softmax over rows (Slen=2048 bf16). Mask pre-applied as -inf.
__global__ __launch_bounds__(256)
void softmax_kernel(bf16* __restrict__ Smat, int Slen)
{
    const int row = blockIdx.x;
    bf16* srow = Smat + (long)row * Slen;

    const int t    = threadIdx.x;
    const int lane = t & 63;
    const int wid  = t >> 6;

    ushort4 u0 = ((const ushort4*)srow)[t * 2];
    ushort4 u1 = ((const ushort4*)srow)[t * 2 + 1];

    float vals[8];
    {
        const unsigned short us[8] = {u0.x, u0.y, u0.z, u0.w, u1.x, u1.y, u1.z, u1.w};
#pragma unroll
        for (int i = 0; i < 8; ++i) {
            unsigned int w = (unsigned int)us[i] << 16;
            vals[i] = *(float*)&w;
        }
    }

    float mx = vals[0];
#pragma unroll
    for (int i = 1; i < 8; ++i) mx = fmaxf(mx, vals[i]);

    __shared__ float red[4];
#pragma unroll
    for (int o = 32; o > 0; o >>= 1) mx = fmaxf(mx, __shfl_xor(mx, o, 64));
    if (lane == 0) red[wid] = mx;
    __syncthreads();
    mx = fmaxf(fmaxf(red[0], red[1]), fmaxf(red[2], red[3]));
    __syncthreads();

    float sum = 0.0f;
#pragma unroll
    for (int i = 0; i < 8; ++i) {
        const float e = __expf(vals[i] - mx);   // exp(-inf - mx) = 0
        vals[i] = e;
        sum += e;
    }
#pragma unroll
    for (int o = 32; o > 0; o >>= 1) sum += __shfl_xor(sum, o, 64);
    if (lane == 0) red[wid] = sum;
    __syncthreads();
    sum = red[0] + red[1] + red[2] + red[3];

    const float inv = 1.0f / sum;
    ushort4 o0, o1;
    o0.x = f2bu(vals[0] * inv); o0.y = f2bu(vals[1] * inv);
    o0.z = f2bu(vals[2] * inv); o0.w = f2bu(vals[3] * inv);
    o1.x = f2bu(vals[4] * inv); o1.y = f2bu(vals[5] * inv);
    o1.z = f2bu(vals[6] * inv); o1.w = f2bu(vals[7] * inv);
    ((ushort4*)srow)[t * 2]     = o0;
    ((ushort4*)srow)[t * 2 + 1] = o1;
}

extern "C" void kernel_launch(void* const* d_in, const int* in_sizes, int n_in,
                              void* d_out, int out_size, void* d_ws, size_t ws_size,
                              hipStream_t stream)
{
    const float* hidden = (const float*)d_in[0];
    const int*   mask   = (const int*)d_in[1];
    const float* Wq_w   = (const float*)d_in[2];
    const float* Wq_b   = (const float*)d_in[3];
    const float* Wk_w   = (const float*)d_in[4];
    const float* Wk_b   = (const float*)d_in[5];
    float* out = (float*)d_out;

    const int B = 8, S = 2048, H = 1024;
    const int M = B * S;               // 16384
    const long MH = (long)M * H;       // 16.7M elems

    // ws (bf16 elems): QK[M][2H] (67MB) | XbT (33.5MB) | Sb (67MB)
    // Xb + Wb (stacked weights) + packed bias aliased inside Sb (dead before scores).
    bf16* QK  = (bf16*)d_ws;
    bf16* XbT = QK + MH * 2;
    bf16* Sb  = XbT + MH;
    bf16* Xb  = Sb;                    // aliased
    bf16* Wb  = Xb + MH;               // [2H][H] = Wq stacked on Wk
    float* biasP = (float*)(Wb + 2L * H * H);  // 2048 floats

    const dim3 blk(256);

    convert_transpose<<<dim3(H / 64, S / 64, B), blk, 0, stream>>>(hidden, Xb, XbT, S, H);
    convert_w2<<<dim3(2 * H * H / 1024), blk, 0, stream>>>(Wq_w, Wk_w, Wb, H * H / 4);
    pack_bias<<<dim3(2 * H / 256), blk, 0, stream>>>(Wq_b, Wk_b, biasP, H);

    // QK = Xb @ [Wq;Wk]^T + [bq;bk]   (merged, N = 2H)
    mfma_gemm_nt<bf16, true, false><<<dim3(M / TM, 2 * H / TN, 1), blk, 0, stream>>>(
        Xb, Wb, biasP, nullptr, QK, 2 * H, H, H, H, 2 * H, 0, 0, 0, 0, 1.0f);

    // Scores_b = (Q_b @ K_b^T)/32, mask applied as -inf in epilogue
    mfma_gemm_nt<bf16, false, true><<<dim3(S / TM, S / TN, B), blk, 0, stream>>>(
        QK, QK + H, nullptr, mask, Sb, S, H, 2 * H, 2 * H, S,
        (long)S * 2 * H, (long)S * 2 * H, (long)S * S, S, 1.0f / 32.0f);

    // softmax in place (mask already -inf)
    softmax_kernel<<<dim3(B * S), blk, 0, stream>>>(Sb, S);

    // Out_b = P_b @ X_b  (B operand = XbT, k-contig)
    mfma_gemm_nt<float, false, false><<<dim3(S / TM, H / TN, B), blk, 0, stream>>>(
        Sb, XbT, nullptr, nullptr, out, H, S, S, S, H,
        (long)S * S, (long)H * S, (long)S * H, 0, 1.0f);
}